// Round 6
// baseline (650.442 us; speedup 1.0000x reference)
//
#include <hip/hip_runtime.h>
#include <hip/hip_bf16.h>
#include <stdint.h>
#include <string.h>

// ---------------------------------------------------------------------------
// Mamba2 block: x@w_in^T -> split(xi,gate) -> depthwise causal conv4 + silu
//               -> *D*silu(gate) -> @w_out^T
// B=4, T=2048, D_MODEL=2048, D_INNER=4096.  GEMMs in bf16 MFMA, fp32 acc.
//
// R6:  256^2/BK=64/8-wave/8-phase, vmcnt(6) publish.  50% MfmaUtil.
// R7/8: A-frag double-buffer -> +32 VGPR past the 256/wave unified cap ->
//      scratch spill (WRITE 147->272 MB).  Discarded.
// R9:  single barrier per phase.  54%, G1 248us.
// R10: 2-D supertile XCD swizzle: FETCH 547->203 MB (L2 fixed) but dur flat
//      -> staging BW was NOT binding; phase lockstep is.  Kept.
// R11: 4 regions/iter + tail-hopped A-reads.  Each K-tile = two regions:
//      R_odd  = {front reads a(0),b0,b1 | stage 4 | Q00,Q01 | TAIL-read a(1)}
//      R_even = {stage 4 | Q11,Q10 (operands pre-read) | vmcnt(4) publish}
//      Tail reads reuse aE/aO after their last use (WAR, +0 VGPR — we are
//      exactly at the 256 unified cap) and drain across the barrier, so
//      R_even is pure-MFMA while other waves' reads stagger -> role
//      diversity for setprio, LDS/MFMA pipes overlap.  Safety: a wave's
//      tail reads complete before its own R_even MFMAs issue; any stage
//      overwriting those rows is behind the end-R_even barrier that wave
//      must reach first (transitive order).  Stages: 4 loads/region
//      (T1q13|T2q02|T2q13|T3q02), publish vmcnt(4) at end R2/R4 (4 newest
//      = that region's own loads).  Barriers 8->4 per iteration.
// ---------------------------------------------------------------------------

#define BT_TOTAL 8192   // B*T
#define DM 2048
#define DI 4096

typedef __attribute__((ext_vector_type(8)))  short short8;   // 8 x bf16
typedef __attribute__((ext_vector_type(16))) float f32x16;   // 32x32 C/D

__device__ __forceinline__ void async_ld16(const void* g, void* l) {
    __builtin_amdgcn_global_load_lds(
        (__attribute__((address_space(1))) void*)g,
        (__attribute__((address_space(3))) void*)l,
        16, 0, 0);
}

__device__ __forceinline__ float bf2f(ushort u) {
    union { uint i; float f; } v; v.i = ((uint)u) << 16; return v.f;
}

__device__ __forceinline__ ushort f2bf_bits(float f) {
    union { __hip_bfloat16 b; ushort u; } v;
    v.b = __float2bfloat16(f);
    return v.u;
}

// LDS regions (ushort indices), 128 KiB total: [A buf0][B buf0][A buf1][B buf1]
#define RA0 0
#define RB0 16384
#define RA1 32768
#define RB1 49152

#define BAR()   asm volatile("s_barrier" ::: "memory")
#define VM4()   asm volatile("s_waitcnt vmcnt(4)" ::: "memory")
#define VM0()   asm volatile("s_waitcnt vmcnt(0)" ::: "memory")
#define PRIO1() __builtin_amdgcn_s_setprio(1)
#define PRIO0() __builtin_amdgcn_s_setprio(0)

// gemm256: C[M,N] = A[M,K] * B[N,K]^T (both K-contiguous), bf16 in, fp32 acc.
// Requires M%256==0, N%256==0, K%128==0, K>=256, grid=(N/256, M/256),
// 512 thr, and (M/256)%8==0, (N/256)%4==0, nwg%256==0 for the supertile map.
template<bool OUT_BF16>
__global__ __launch_bounds__(512, 2) void gemm256_kernel(
    const ushort* __restrict__ A, const ushort* __restrict__ B,
    void* __restrict__ Cp, int M, int N, int K)
{
    __shared__ ushort lds[65536];   // 128 KiB

    const int tid  = threadIdx.x;
    const int lane = tid & 63;
    const int wave = tid >> 6;      // 8 waves: 2 (M) x 4 (N)
    const int wm   = wave >> 2;     // 0..1 -> 128 rows each
    const int wn   = wave & 3;      // 0..3 -> 64 cols each
    const int l31  = lane & 31;
    const int half = lane >> 5;

    // ---- 2-D supertile XCD swizzle (R10).  Supertile = 8 bm-rows x 4
    //      bn-cols = 32 blocks = one XCD's concurrent set.
    const int nbx = gridDim.x;
    const int nwg = nbx * gridDim.y;
    const int orig = blockIdx.y * nbx + blockIdx.x;
    const int xcd  = orig & 7;
    const int t    = orig >> 3;              // [0, nwg/8)
    const int sloc = t >> 5;                 // supertile index within XCD
    const int u    = t & 31;                 // block within supertile
    const int spx  = (nwg >> 5) >> 3;        // supertiles per XCD
    const int g    = xcd * spx + sloc;       // global supertile id
    const int scols = nbx >> 2;              // supertile grid width (nbx/SN)
    const int sr   = g / scols;
    const int sc   = g - sr * scols;
    const int bm   = (sr * 8 + (u >> 2)) * 256;
    const int bn   = (sc * 4 + (u & 3)) * 256;

    // ---- staging precompute: thread tid covers 16B chunk (tid) of a
    //      64-row x 64-col quarter; source chunk pre-swizzled by f(row).
    const int rq = tid >> 3;                 // row within quarter
    const int jq = tid & 7;                  // chunk within row
    const int fq = (rq ^ (rq >> 3)) & 7;     // == f(qrow + rq) for qrow%64==0
    const int goffA = (bm + rq) * K + ((jq ^ fq) * 8);
    const int goffB = (bn + rq) * K + ((jq ^ fq) * 8);
    const int dst8  = tid * 8;               // linear LDS dest (ushorts)

    // ---- reader precompute (32x32x16 frags; logical chunk q = ks*2 + half,
    //      physical chunk = q ^ ((frag&1)*4) ^ flane)
    const int flane = (l31 ^ (l31 >> 3)) & 7;
    const int cl8   = (half ^ flane) * 8;            // chunk-xor base, x8 ush
    const int aBase = (wm * 128 + l31) * 64;         // within A region
    const int bBase = (wn * 64  + l31) * 64;         // within B region

    f32x16 acc[4][2];
#pragma unroll
    for (int m = 0; m < 4; ++m)
#pragma unroll
        for (int n = 0; n < 2; ++n)
#pragma unroll
            for (int r = 0; r < 16; ++r)
                acc[m][n][r] = 0.f;

    short8 aE[4], aO[4], b0[4], b1[4];   // R6 register set — no spill

#define STA(P, QROW, REG) async_ld16((P) + (size_t)(QROW) * K + goffA, \
                                     &lds[(REG) + (QROW) * 64 + dst8])
#define STB(P, QROW, REG) async_ld16((P) + (size_t)(QROW) * K + goffB, \
                                     &lds[(REG) + (QROW) * 64 + dst8])

#define RDA(MH, REG) do { \
    _Pragma("unroll") \
    for (int ks = 0; ks < 4; ++ks) { \
        aE[ks] = *(const short8*)&lds[(REG) + aBase + (MH)*4096 + (cl8 ^ (ks<<4))]; \
        aO[ks] = *(const short8*)&lds[(REG) + aBase + (MH)*4096 + 2048 + (cl8 ^ (ks<<4) ^ 32)]; \
    } } while (0)

#define RDB(DSTV, NF, REG) do { \
    _Pragma("unroll") \
    for (int ks = 0; ks < 4; ++ks) { \
        DSTV[ks] = *(const short8*)&lds[(REG) + bBase + (NF)*2048 + (cl8 ^ (ks<<4) ^ ((NF)<<5))]; \
    } } while (0)

#define MMA(MH, NH, BF) do { \
    _Pragma("unroll") \
    for (int ks = 0; ks < 4; ++ks) { \
        acc[(MH)*2    ][(NH)] = __builtin_amdgcn_mfma_f32_32x32x16_bf16( \
            aE[ks], BF[ks], acc[(MH)*2    ][(NH)], 0, 0, 0); \
        acc[(MH)*2 + 1][(NH)] = __builtin_amdgcn_mfma_f32_32x32x16_bf16( \
            aO[ks], BF[ks], acc[(MH)*2 + 1][(NH)], 0, 0, 0); \
    } } while (0)

    // ---- prologue: T0 (8 quarters) + T1 q0,q2 (4).  vmcnt(4) lands T0;
    //      T1's 4 stay in flight (published end-R2 of iter 0).
    {
        STA(A, 0, RA0);  STA(A, 128, RA0);
        STB(B, 0, RB0);  STB(B, 128, RB0);
        STA(A, 64, RA0); STA(A, 192, RA0);
        STB(B, 64, RB0); STB(B, 192, RB0);
        const ushort* Ap = A + 64;
        const ushort* Bp = B + 64;
        STA(Ap, 0, RA1);  STA(Ap, 128, RA1);
        STB(Bp, 0, RB1);  STB(Bp, 128, RB1);
        VM4(); BAR();
    }

    const int NITER = K >> 7;   // 2 K-tiles (T0=buf0, T1=buf1) per iteration
    for (int i = 0; i < NITER; ++i) {
        const bool last = (i == NITER - 1);
        const int kT1 = 128 * i + 64;
        const int kT2 = 128 * i + 128;
        const int kT3 = 128 * i + 192;

        // R1: T0 half0 (Q00,Q01) | stage T1 q1,q3 -> buf1 | tail-read a(1)
        RDA(0, RA0); RDB(b0, 0, RB0);
        STB(B + kT1, 64, RB1); STB(B + kT1, 192, RB1);
        STA(A + kT1, 64, RA1); STA(A + kT1, 192, RA1);
        RDB(b1, 1, RB0);
        PRIO1(); MMA(0, 0, b0); MMA(0, 1, b1); PRIO0();
        RDA(1, RA0);                 // tail: drains across barrier into R2
        BAR();

        // R2: T0 half1 (Q11,Q10) pure-MFMA | stage T2 q0,q2 | publish T1
        if (!last) { STA(A + kT2, 0, RA0); STA(A + kT2, 128, RA0);
                     STB(B + kT2, 0, RB0); STB(B + kT2, 128, RB0); }
        PRIO1(); MMA(1, 1, b1); MMA(1, 0, b0); PRIO0();
        if (last) { VM0(); } else { VM4(); }
        BAR();

        // R3: T1 half0 (Q00,Q01) from buf1 | stage T2 q1,q3 | tail-read a(1)
        RDA(0, RA1); RDB(b0, 0, RB1);
        if (!last) { STB(B + kT2, 64, RB0); STB(B + kT2, 192, RB0);
                     STA(A + kT2, 64, RA0); STA(A + kT2, 192, RA0); }
        RDB(b1, 1, RB1);
        PRIO1(); MMA(0, 0, b0); MMA(0, 1, b1); PRIO0();
        RDA(1, RA1);
        BAR();

        // R4: T1 half1 (Q11,Q10) pure-MFMA | stage T3 q0,q2 | publish T2
        if (!last) { STA(A + kT3, 0, RA1); STA(A + kT3, 128, RA1);
                     STB(B + kT3, 0, RB1); STB(B + kT3, 128, RB1); }
        PRIO1(); MMA(1, 1, b1); MMA(1, 0, b0); PRIO0();
        if (!last) { VM4(); BAR(); }
    }

    // ---- epilogue. 32x32 C/D layout (verified m74/m101):
    //   col = lane&31, row = (reg&3) + 8*(reg>>2) + 4*(lane>>5)
    const int col0 = bn + wn * 64 + l31;
    const int row0 = bm + wm * 128 + 4 * half;
    if (OUT_BF16) {
        __hip_bfloat16* C = (__hip_bfloat16*)Cp;
#pragma unroll
        for (int m = 0; m < 4; ++m)
#pragma unroll
            for (int n = 0; n < 2; ++n)
#pragma unroll
                for (int r = 0; r < 16; ++r) {
                    const int row = row0 + m * 32 + (r & 3) + 8 * (r >> 2);
                    C[(size_t)row * (size_t)N + col0 + n * 32] =
                        __float2bfloat16(acc[m][n][r]);
                }
    } else {
        float* C = (float*)Cp;
#pragma unroll
        for (int m = 0; m < 4; ++m)
#pragma unroll
            for (int n = 0; n < 2; ++n)
#pragma unroll
                for (int r = 0; r < 16; ++r) {
                    const int row = row0 + m * 32 + (r & 3) + 8 * (r >> 2);
                    C[(size_t)row * (size_t)N + col0 + n * 32] = acc[m][n][r];
                }
    }
}

// Depthwise causal conv (4 taps) + silu, * D, * silu(gate).  8 d's / thread.
__global__ __launch_bounds__(256) void conv_silu_kernel(
    const ushort* __restrict__ xp,   // bf16 [8192][8192]
    const float* __restrict__ cw,    // [4096][4]
    const float* __restrict__ cb,    // [4096]
    const float* __restrict__ Dv,    // [4096]
    ushort* __restrict__ h)          // bf16 [8192][4096]
{
    const int v  = blockIdx.x * 256 + threadIdx.x;   // over 8192*512
    const int d8 = (v & 511) * 8;
    const int bt = v >> 9;
    const int t  = bt & 2047;

    const uint4 gv = *(const uint4*)(xp + (size_t)bt * (2 * DI) + DI + d8);
    uint4 tap[4];
#pragma unroll
    for (int k = 0; k < 4; ++k) {
        const int tt = t - 3 + k;
        if (tt >= 0)
            tap[k] = *(const uint4*)(xp + (size_t)(bt - 3 + k) * (2 * DI) + d8);
        else
            tap[k] = (uint4){0u, 0u, 0u, 0u};
    }

    const float4* cwv = (const float4*)(cw + (size_t)d8 * 4);   // 8 x float4
    const float4  cb0 = *(const float4*)(cb + d8);
    const float4  cb1 = *(const float4*)(cb + d8 + 4);
    const float4  dv0 = *(const float4*)(Dv + d8);
    const float4  dv1 = *(const float4*)(Dv + d8 + 4);
    const float cbs[8] = {cb0.x, cb0.y, cb0.z, cb0.w, cb1.x, cb1.y, cb1.z, cb1.w};
    const float dvs[8] = {dv0.x, dv0.y, dv0.z, dv0.w, dv1.x, dv1.y, dv1.z, dv1.w};

    ushort res[8];
#pragma unroll
    for (int j = 0; j < 8; ++j) {
        float a = cbs[j];
        const float4 w = cwv[j];
        const float wk[4] = {w.x, w.y, w.z, w.w};
#pragma unroll
        for (int k = 0; k < 4; ++k) {
            const uint u = ((const uint*)&tap[k])[j >> 1];
            const ushort us = (j & 1) ? (ushort)(u >> 16) : (ushort)(u & 0xffff);
            a += bf2f(us) * wk[k];
        }
        const uint gu = ((const uint*)&gv)[j >> 1];
        const ushort gs = (j & 1) ? (ushort)(gu >> 16) : (ushort)(gu & 0xffff);
        const float g = bf2f(gs);
        const float sc = a / (1.f + __expf(-a));
        const float sg = g / (1.f + __expf(-g));
        res[j] = f2bf_bits(sc * dvs[j] * sg);
    }
    *(uint4*)(h + (size_t)bt * DI + d8) = *(const uint4*)res;
}

__global__ __launch_bounds__(256) void f32_to_bf16_x4(
    const float* __restrict__ in, __hip_bfloat16* __restrict__ out, int n4)
{
    const int i = blockIdx.x * 256 + threadIdx.x;
    if (i >= n4) return;
    const float4 v = *(const float4*)(in + (size_t)i * 4);
    union { __hip_bfloat16 hh[4]; ushort4 u; } cv;
    cv.hh[0] = __float2bfloat16(v.x);
    cv.hh[1] = __float2bfloat16(v.y);
    cv.hh[2] = __float2bfloat16(v.z);
    cv.hh[3] = __float2bfloat16(v.w);
    *(ushort4*)((ushort*)out + (size_t)i * 4) = cv.u;
}

extern "C" void kernel_launch(void* const* d_in, const int* in_sizes, int n_in,
                              void* d_out, int out_size, void* d_ws, size_t ws_size,
                              hipStream_t stream)
{
    const float* x     = (const float*)d_in[0];   // [4,2048,2048]
    const float* w_in  = (const float*)d_in[1];   // [8192,2048]
    const float* w_out = (const float*)d_in[2];   // [2048,4096]
    const float* cw    = (const float*)d_in[3];   // [4096,1,4]
    const float* cb    = (const float*)d_in[4];   // [4096]
    const float* Dv    = (const float*)d_in[5];   // [4096]
    float* out = (float*)d_out;                   // [4,2048,2048]

    // Workspace layout (208 MiB):
    //   [0, 128M)        x_proj bf16 [8192][8192]
    //   [128M, 192M)     phase 1: xb (32M) + winb (32M); phase 2: h bf16 (64M)
    //   [192M, 208M)     woutb [2048][4096] bf16
    char* wsc = (char*)d_ws;
    __hip_bfloat16* xproj = (__hip_bfloat16*)wsc;
    __hip_bfloat16* xb    = (__hip_bfloat16*)(wsc + (size_t)134217728);
    __hip_bfloat16* winb  = (__hip_bfloat16*)(wsc + (size_t)134217728 + 33554432);
    __hip_bfloat16* hbuf  = (__hip_bfloat16*)(wsc + (size_t)134217728);  // aliases xb/winb
    __hip_bfloat16* woutb = (__hip_bfloat16*)(wsc + (size_t)201326592);

    // 1) fp32 -> bf16 converts
    f32_to_bf16_x4<<<(BT_TOTAL * DM / 4 + 255) / 256, 256, 0, stream>>>(x, xb, BT_TOTAL * DM / 4);
    f32_to_bf16_x4<<<(2 * DI * DM / 4 + 255) / 256, 256, 0, stream>>>(w_in, winb, 2 * DI * DM / 4);
    f32_to_bf16_x4<<<(DM * DI / 4 + 255) / 256, 256, 0, stream>>>(w_out, woutb, DM * DI / 4);

    // 2) GEMM1: x_proj[bt,d] = sum_c x[bt,c] * w_in[d,c]   (M=8192,N=8192,K=2048)
    gemm256_kernel<true><<<dim3((2 * DI) / 256, BT_TOTAL / 256), 512, 0, stream>>>(
        (const ushort*)xb, (const ushort*)winb, xproj, BT_TOTAL, 2 * DI, DM);

    // 3) conv + silu + gate  (writes hbuf over dead xb/winb — stream-ordered)
    conv_silu_kernel<<<(BT_TOTAL * DI / 8) / 256, 256, 0, stream>>>(
        (const ushort*)xproj, cw, cb, Dv, (ushort*)hbuf);

    // 4) GEMM2: out[bt,c] = sum_d h[bt,d] * w_out[c,d]   (M=8192,N=2048,K=4096)
    gemm256_kernel<false><<<dim3(DM / 256, BT_TOTAL / 256), 512, 0, stream>>>(
        (const ushort*)hbuf, (const ushort*)woutb, out, BT_TOTAL, DM, DI);
}